// Round 5
// baseline (186.563 us; speedup 1.0000x reference)
//
#include <hip/hip_runtime.h>
#include <hip/hip_bf16.h>
#include <stdint.h>

#define BS   16384
#define NC   2000
#define NCP  2048            // padded N (wn zero-filled rows 2000..2047)
#define EMB  512
#define NAUX 5
#define NCHUNK 32            // es/key partial chunks = col/64 stripe index

typedef __bf16 bf16x8 __attribute__((ext_vector_type(8)));
typedef float  f32x4  __attribute__((ext_vector_type(4)));

// ---------------------------------------------------------------------------
// Kernel 1: row-normalize features (rows [0,BS)) and word_embed ([BS,BS+NC))
// into bf16; zero-fill wn padding rows [NC,NCP). One wave per row.
// ---------------------------------------------------------------------------
__global__ __launch_bounds__(256) void norm_kernel(
    const float* __restrict__ feat, const float* __restrict__ wemb,
    __bf16* __restrict__ fn, __bf16* __restrict__ wn)
{
    const int lane = threadIdx.x & 63;
    const int row  = blockIdx.x * 4 + (threadIdx.x >> 6);

    if (row >= BS + NC) {  // padding rows of wn -> zeros (masked in epilogue)
        bf16x8 z = {};
        ((bf16x8*)(wn + (size_t)(row - BS) * EMB))[lane] = z;
        return;
    }
    const float* src;
    __bf16* dst;
    if (row < BS) { src = feat + (size_t)row * EMB;        dst = fn + (size_t)row * EMB; }
    else          { src = wemb + (size_t)(row - BS) * EMB; dst = wn + (size_t)(row - BS) * EMB; }

    float4 x0 = ((const float4*)src)[lane * 2];
    float4 x1 = ((const float4*)src)[lane * 2 + 1];
    float ss = x0.x*x0.x + x0.y*x0.y + x0.z*x0.z + x0.w*x0.w
             + x1.x*x1.x + x1.y*x1.y + x1.z*x1.z + x1.w*x1.w;
    #pragma unroll
    for (int m = 1; m < 64; m <<= 1) ss += __shfl_xor(ss, m, 64);
    const float scale = 1.0f / fmaxf(sqrtf(ss), 1e-12f);

    bf16x8 o;
    o[0] = (__bf16)(x0.x * scale); o[1] = (__bf16)(x0.y * scale);
    o[2] = (__bf16)(x0.z * scale); o[3] = (__bf16)(x0.w * scale);
    o[4] = (__bf16)(x1.x * scale); o[5] = (__bf16)(x1.y * scale);
    o[6] = (__bf16)(x1.z * scale); o[7] = (__bf16)(x1.w * scale);
    ((bf16x8*)dst)[lane] = o;
}

// ---------------------------------------------------------------------------
// Kernel 2: A-resident GEMM + fused exp-sum / packed-argmax epilogue.
//   Block = 512 threads (8 waves). A panel (64 rows x 512 K, 64 KB) staged
//   ONCE into XOR-swizzled LDS (phys_kbyte = kbyte ^ ((row&7)<<4)) -> one
//   barrier total, zero K-loop barriers. Each wave: 64 rows x 64 cols via
//   4x4 of mfma_f32_16x16x32_bf16 (verified layouts). B frags streamed from
//   global; wn = 2 MB -> every read is an L2 hit.
//   Grid = 256 mTiles x 4 col-splits; consecutive blocks share the A panel.
// mfma_f32_16x16x32_bf16 verified layouts:
//   A frag: lane(m=lane&15, q=lane>>4) holds A[m][q*8+j]
//   B frag: lane(n=lane&15, q)         holds B[q*8+j][n] = wn[n][q*8+j]
//   C/D:    col(n) = lane&15, row(m) = q*4 + reg
// ---------------------------------------------------------------------------
__global__ __launch_bounds__(512, 4) void main_kernel(
    const __bf16* __restrict__ fn, const __bf16* __restrict__ wn,
    float* __restrict__ es_part, unsigned* __restrict__ key_part)
{
    __shared__ __align__(16) char As[65536];   // 64 rows x 1024 B, swizzled

    const int tid   = threadIdx.x;
    const int lane  = tid & 63;
    const int l15   = lane & 15;
    const int quad  = lane >> 4;
    const int wv    = tid >> 6;                // 0..7
    const int mTile = blockIdx.x >> 2;
    const int nsp   = blockIdx.x & 3;
    const int mBase = mTile * 64;
    const int colBase = nsp * 512 + wv * 64;

    // --- Stage A panel (one pass, coalesced 128B per 8 lanes, swizzled store)
    {
        const int row = tid >> 3;              // 0..63
        const int t8  = tid & 7;
        const char* gsrc = (const char*)(fn + (size_t)(mBase + row) * EMB);
        char* ldst = As + row * 1024;
        const int sw = (row & 7) << 4;
        #pragma unroll
        for (int i = 0; i < 8; ++i) {
            const int kb = t8 * 16 + i * 128;
            *(bf16x8*)(ldst + (kb ^ sw)) = *(const bf16x8*)(gsrc + kb);
        }
    }
    __syncthreads();

    // --- K loop: no barriers. 4 B-frag global loads + 4 A-frag LDS reads +
    //     16 MFMAs per K=32 step.
    f32x4 acc[4][4] = {};
    const char* bptr[4];
    #pragma unroll
    for (int ni = 0; ni < 4; ++ni)
        bptr[ni] = (const char*)(wn + (size_t)(colBase + ni * 16 + l15) * EMB) + quad * 16;

    const int aswz = (l15 & 7) << 4;

    for (int kc = 0; kc < 16; ++kc) {
        const int kb = kc * 64 + quad * 16;
        bf16x8 bF[4], aF[4];
        #pragma unroll
        for (int ni = 0; ni < 4; ++ni)
            bF[ni] = *(const bf16x8*)(bptr[ni] + kc * 64);
        #pragma unroll
        for (int mi = 0; mi < 4; ++mi)
            aF[mi] = *(const bf16x8*)(As + (mi * 16 + l15) * 1024 + (kb ^ aswz));
        #pragma unroll
        for (int mi = 0; mi < 4; ++mi)
            #pragma unroll
            for (int ni = 0; ni < 4; ++ni)
                acc[mi][ni] = __builtin_amdgcn_mfma_f32_16x16x32_bf16(
                    aF[mi], bF[ni], acc[mi][ni], 0, 0, 0);
    }

    // --- Epilogue: es += exp2((v-1)*20*log2e); packed argmax; per-wave chunk.
    const float C20 = 28.853900817779268f;     // 20*log2(e)
    const int chunk = nsp * 8 + wv;
    #pragma unroll
    for (int mi = 0; mi < 4; ++mi) {
        float    es[4] = {0.f, 0.f, 0.f, 0.f};
        unsigned km[4] = {0u, 0u, 0u, 0u};
        #pragma unroll
        for (int ni = 0; ni < 4; ++ni) {
            const int col = colBase + ni * 16 + l15;
            const unsigned colenc = 2047u - (unsigned)col;
            const bool valid = (col < NC);
            #pragma unroll
            for (int r = 0; r < 4; ++r) {
                float v = valid ? acc[mi][ni][r] : -3.0f;
                es[r] += exp2f((v - 1.0f) * C20);
                unsigned u = __float_as_uint(v);
                unsigned k = u ^ (unsigned)(((int)u >> 31) | 0x80000000);
                unsigned pk = (k & 0xFFFFF800u) | colenc;  // bigger v, then smaller col
                km[r] = pk > km[r] ? pk : km[r];
            }
        }
        #pragma unroll
        for (int r = 0; r < 4; ++r) {
            #pragma unroll
            for (int m = 1; m < 16; m <<= 1) {
                es[r] += __shfl_xor(es[r], m, 64);
                unsigned x = __shfl_xor(km[r], m, 64);
                km[r] = x > km[r] ? x : km[r];
            }
        }
        if (l15 == 0) {
            #pragma unroll
            for (int r = 0; r < 4; ++r) {
                const int row = mBase + mi * 16 + quad * 4 + r;
                es_part [chunk * BS + row] = es[r];
                key_part[chunk * BS + row] = km[r];
            }
        }
    }
}

// ---------------------------------------------------------------------------
// Kernel 3: gather pred[i,label[i]] and sum_j pred[i,aux[i,j]]. One wave/row.
// ---------------------------------------------------------------------------
__global__ __launch_bounds__(256) void gather_kernel(
    const __bf16* __restrict__ fn, const __bf16* __restrict__ wn,
    const int* __restrict__ label, const int* __restrict__ aux,
    float* __restrict__ tgt, float* __restrict__ auxs)
{
    const int lane = threadIdx.x & 63;
    const int row  = blockIdx.x * 4 + (threadIdx.x >> 6);

    bf16x8 f8 = *((const bf16x8*)fn + (size_t)row * (EMB / 8) + lane);
    float fv[8];
    #pragma unroll
    for (int j = 0; j < 8; ++j) fv[j] = (float)f8[j];

    int cols[6];
    cols[0] = label[row];
    #pragma unroll
    for (int j = 0; j < NAUX; ++j) cols[j + 1] = aux[row * NAUX + j];

    float res[6];
    #pragma unroll
    for (int c = 0; c < 6; ++c) {
        bf16x8 w8 = *((const bf16x8*)wn + (size_t)cols[c] * (EMB / 8) + lane);
        float d = 0.f;
        #pragma unroll
        for (int j = 0; j < 8; ++j) d += fv[j] * (float)w8[j];
        #pragma unroll
        for (int m = 1; m < 64; m <<= 1) d += __shfl_xor(d, m, 64);
        res[c] = d;
    }
    if (lane == 0) {
        tgt[row]  = res[0] * 20.0f;
        auxs[row] = (res[1] + res[2] + res[3] + res[4] + res[5]) * 20.0f;
    }
}

// ---------------------------------------------------------------------------
// Kernel 4: combine 32 chunk partials per row -> loss_i, acc_i; block-reduce.
// loss_i = 20 + log(es) - 0.95*tgt_i - 0.01*auxsum_i
// ---------------------------------------------------------------------------
__global__ __launch_bounds__(256) void fin1_kernel(
    const float* __restrict__ es_part, const unsigned* __restrict__ key_part,
    const float* __restrict__ tgt, const float* __restrict__ auxs,
    const int* __restrict__ label, float* __restrict__ blk)
{
    const int row = blockIdx.x * 256 + threadIdx.x;
    float es = 0.f;
    unsigned k = 0u;
    #pragma unroll
    for (int c = 0; c < NCHUNK; ++c) {
        es += es_part[c * BS + row];
        unsigned x = key_part[c * BS + row];
        k = x > k ? x : k;
    }
    const int amax = 2047 - (int)(k & 0x7FFu);

    float loss = 20.0f + logf(es) - 0.95f * tgt[row] - 0.01f * auxs[row];
    float acc  = (amax == label[row]) ? 1.0f : 0.0f;

    #pragma unroll
    for (int m = 1; m < 64; m <<= 1) {
        loss += __shfl_xor(loss, m, 64);
        acc  += __shfl_xor(acc, m, 64);
    }
    __shared__ float sl[4], sa[4];
    const int wv = threadIdx.x >> 6;
    if ((threadIdx.x & 63) == 0) { sl[wv] = loss; sa[wv] = acc; }
    __syncthreads();
    if (threadIdx.x == 0) {
        blk[blockIdx.x]      = sl[0] + sl[1] + sl[2] + sl[3];
        blk[64 + blockIdx.x] = sa[0] + sa[1] + sa[2] + sa[3];
    }
}

__global__ __launch_bounds__(64) void fin2_kernel(
    const float* __restrict__ blk, float* __restrict__ out)
{
    float l = blk[threadIdx.x];
    float a = blk[64 + threadIdx.x];
    #pragma unroll
    for (int m = 1; m < 64; m <<= 1) {
        l += __shfl_xor(l, m, 64);
        a += __shfl_xor(a, m, 64);
    }
    if (threadIdx.x == 0) {
        out[0] = l / (float)BS;
        out[1] = a / (float)BS;
    }
}

// ---------------------------------------------------------------------------
// Workspace layout (bytes):
//   fn   @ 0         (16,777,216)  BS x 512 bf16
//   wn   @ 16777216  ( 2,097,152)  NCP(2048) x 512 bf16 (rows >=2000 zero)
//   es   @ 18874368  ( 2,097,152)  [32][BS] f32
//   key  @ 20971520  ( 2,097,152)  [32][BS] u32
//   tgt  @ 23068672  (    65,536)
//   auxs @ 23134208  (    65,536)
//   blk  @ 23199744  (       512)
// ---------------------------------------------------------------------------
extern "C" void kernel_launch(void* const* d_in, const int* in_sizes, int n_in,
                              void* d_out, int out_size, void* d_ws, size_t ws_size,
                              hipStream_t stream)
{
    const float* feat  = (const float*)d_in[0];
    const float* wemb  = (const float*)d_in[1];
    const int*   label = (const int*)d_in[2];
    const int*   aux   = (const int*)d_in[3];

    char* ws = (char*)d_ws;
    __bf16*   fn   = (__bf16*)(ws);
    __bf16*   wn   = (__bf16*)(ws + 16777216);
    float*    es   = (float*)(ws + 18874368);
    unsigned* key  = (unsigned*)(ws + 20971520);
    float*    tgt  = (float*)(ws + 23068672);
    float*    auxs = (float*)(ws + 23134208);
    float*    blk  = (float*)(ws + 23199744);
    float*    out  = (float*)d_out;

    hipLaunchKernelGGL(norm_kernel, dim3((BS + NCP) / 4), dim3(256), 0, stream,
                       feat, wemb, fn, wn);
    hipLaunchKernelGGL(main_kernel, dim3((BS / 64) * 4), dim3(512), 0, stream,
                       fn, wn, es, key);
    hipLaunchKernelGGL(gather_kernel, dim3(BS / 4), dim3(256), 0, stream,
                       fn, wn, label, aux, tgt, auxs);
    hipLaunchKernelGGL(fin1_kernel, dim3(BS / 256), dim3(256), 0, stream,
                       es, key, tgt, auxs, label, blk);
    hipLaunchKernelGGL(fin2_kernel, dim3(1), dim3(64), 0, stream, blk, out);
}

// Round 6
// 170.965 us; speedup vs baseline: 1.0912x; 1.0912x over previous
//
#include <hip/hip_runtime.h>
#include <hip/hip_bf16.h>
#include <stdint.h>

#define BS   16384
#define NC   2000
#define NCP  2048            // padded N (wn zero-filled rows 2000..2047)
#define EMB  512
#define NAUX 5
#define NCHUNK 32            // es/key partial chunks: nTile*2 + wvN

typedef __bf16 bf16x8 __attribute__((ext_vector_type(8)));
typedef float  f32x4  __attribute__((ext_vector_type(4)));

// ---------------------------------------------------------------------------
// Kernel 1: row-normalize features (rows [0,BS)) and word_embed ([BS,BS+NC))
// into bf16; zero-fill wn padding rows [NC,NCP). 16 lanes per row.
// ---------------------------------------------------------------------------
__global__ __launch_bounds__(256) void norm_kernel(
    const float* __restrict__ feat, const float* __restrict__ wemb,
    __bf16* __restrict__ fn, __bf16* __restrict__ wn)
{
    const int sub = threadIdx.x & 15;                    // lane-in-row
    const int row = blockIdx.x * 16 + (threadIdx.x >> 4);

    if (row >= BS + NC) {  // padding rows of wn -> zeros (masked in epilogue)
        bf16x8 z = {};
        bf16x8* d = (bf16x8*)(wn + (size_t)(row - BS) * EMB) + sub * 4;
        #pragma unroll
        for (int i = 0; i < 4; ++i) d[i] = z;
        return;
    }
    const float* src;
    __bf16* dst;
    if (row < BS) { src = feat + (size_t)row * EMB;        dst = fn + (size_t)row * EMB; }
    else          { src = wemb + (size_t)(row - BS) * EMB; dst = wn + (size_t)(row - BS) * EMB; }

    const float4* s4 = (const float4*)src + sub * 8;     // 32 floats per lane
    float4 x[8];
    float ss = 0.f;
    #pragma unroll
    for (int i = 0; i < 8; ++i) {
        x[i] = s4[i];
        ss += x[i].x * x[i].x + x[i].y * x[i].y + x[i].z * x[i].z + x[i].w * x[i].w;
    }
    #pragma unroll
    for (int m = 1; m < 16; m <<= 1) ss += __shfl_xor(ss, m, 64);
    const float scale = 1.0f / fmaxf(sqrtf(ss), 1e-12f);

    bf16x8* d = (bf16x8*)dst + sub * 4;
    #pragma unroll
    for (int i = 0; i < 4; ++i) {
        bf16x8 o;
        o[0] = (__bf16)(x[2*i].x   * scale); o[1] = (__bf16)(x[2*i].y   * scale);
        o[2] = (__bf16)(x[2*i].z   * scale); o[3] = (__bf16)(x[2*i].w   * scale);
        o[4] = (__bf16)(x[2*i+1].x * scale); o[5] = (__bf16)(x[2*i+1].y * scale);
        o[6] = (__bf16)(x[2*i+1].z * scale); o[7] = (__bf16)(x[2*i+1].w * scale);
        d[i] = o;
    }
}

// ---------------------------------------------------------------------------
// Kernel 2: m97-structure GEMM: 128x128 tile, BK=64, 4 waves in 2x2, A and B
// staged via global_load_lds width=16 (explicit s_waitcnt before barrier —
// the builtin has no SSA result so the compiler will NOT wait for it).
// LDS layout: row-major 128 rows x 128 B, column-16B-chunk XOR-swizzled:
//   LDS(row, chunk_phys = chunk_log ^ (row&7)) holds global chunk_log.
//   (Legal despite the builtin's fixed LDS-side lane mapping because the
//   per-lane GLOBAL address is arbitrary.) Frag reads then touch all 32
//   banks (8 phases, the b128 minimum) instead of 16 banks.
// Fused epilogue: exp-sum + packed argmax partials, [chunk][row] layout.
// mfma_f32_16x16x32_bf16 verified layouts:
//   A frag: lane(m=lane&15, q=lane>>4) holds A[m][q*8+j]
//   B frag: lane(n=lane&15, q)         holds B[q*8+j][n] = wn[n][q*8+j]
//   C/D:    col(n) = lane&15, row(m) = q*4 + reg
// ---------------------------------------------------------------------------
__global__ __launch_bounds__(256) void main_kernel(
    const __bf16* __restrict__ fn, const __bf16* __restrict__ wn,
    float* __restrict__ es_part, unsigned* __restrict__ key_part)
{
    __shared__ __align__(16) __bf16 As[128 * 64];
    __shared__ __align__(16) __bf16 Bs[128 * 64];

    const int tid   = threadIdx.x;
    const int lane  = tid & 63;
    const int l15   = lane & 15;
    const int quad  = lane >> 4;
    const int wv    = tid >> 6;
    const int wvM   = wv >> 1;
    const int wvN   = wv & 1;
    const int mTile = blockIdx.x >> 4;   // 128 m-tiles
    const int nTile = blockIdx.x & 15;   // 16 n-tiles (N padded to 2048)

    const __bf16* fbase = fn + (size_t)mTile * 128 * EMB;
    const __bf16* wbase = wn + (size_t)nTile * 128 * EMB;

    // Per-lane staging geometry: slot = wv*4+j covers LDS rows slot*8..+8.
    // Lane L: row_in_slot = L>>3, chunk_phys = L&7, chunk_log = (L&7)^(L>>3).
    const int sRowIn = lane >> 3;                 // 0..7
    const int sChunk = (lane & 7) ^ sRowIn;       // logical 16B chunk to fetch
    f32x4 acc[4][4] = {};

    for (int kk = 0; kk < EMB; kk += 64) {
        __syncthreads();                          // previous tile's readers done
        #pragma unroll
        for (int j = 0; j < 4; ++j) {
            const int slot = wv * 4 + j;
            const size_t goff = (size_t)(slot * 8 + sRowIn) * EMB + kk + sChunk * 8;
            __builtin_amdgcn_global_load_lds(
                (const __attribute__((address_space(1))) void*)(fbase + goff),
                (__attribute__((address_space(3))) void*)(As + slot * 512), 16, 0, 0);
            __builtin_amdgcn_global_load_lds(
                (const __attribute__((address_space(1))) void*)(wbase + goff),
                (__attribute__((address_space(3))) void*)(Bs + slot * 512), 16, 0, 0);
        }
        __builtin_amdgcn_s_waitcnt(0);            // drain global->LDS DMA
        __syncthreads();                          // staged tile visible to all

        #pragma unroll
        for (int kc = 0; kc < 2; ++kc) {
            bf16x8 aF[4], bF[4];
            #pragma unroll
            for (int i = 0; i < 4; ++i) {
                const int ar = wvM * 64 + i * 16 + l15;
                const int br = wvN * 64 + i * 16 + l15;
                const int ca = ((kc * 4 + quad) ^ (ar & 7)) * 8;
                const int cb = ((kc * 4 + quad) ^ (br & 7)) * 8;
                aF[i] = *(const bf16x8*)(As + ar * 64 + ca);
                bF[i] = *(const bf16x8*)(Bs + br * 64 + cb);
            }
            #pragma unroll
            for (int mi = 0; mi < 4; ++mi)
                #pragma unroll
                for (int ni = 0; ni < 4; ++ni)
                    acc[mi][ni] = __builtin_amdgcn_mfma_f32_16x16x32_bf16(
                        aF[mi], bF[ni], acc[mi][ni], 0, 0, 0);
        }
    }

    // Epilogue: es += exp2((v-1)*20*log2e); packed argmax; per-(nTile,wvN) chunk.
    const float C20 = 28.853900817779268f;  // 20*log2(e)
    const int chunk = nTile * 2 + wvN;
    #pragma unroll
    for (int mi = 0; mi < 4; ++mi) {
        float    es[4] = {0.f, 0.f, 0.f, 0.f};
        unsigned km[4] = {0u, 0u, 0u, 0u};
        #pragma unroll
        for (int ni = 0; ni < 4; ++ni) {
            const int col = nTile * 128 + wvN * 64 + ni * 16 + l15;
            const unsigned colenc = 2047u - (unsigned)col;
            const bool valid = (col < NC);
            #pragma unroll
            for (int r = 0; r < 4; ++r) {
                float v = valid ? acc[mi][ni][r] : -3.0f;
                es[r] += exp2f((v - 1.0f) * C20);
                unsigned u = __float_as_uint(v);
                unsigned k = u ^ (unsigned)(((int)u >> 31) | 0x80000000);
                unsigned pk = (k & 0xFFFFF800u) | colenc;  // bigger v, then smaller col
                km[r] = pk > km[r] ? pk : km[r];
            }
        }
        #pragma unroll
        for (int r = 0; r < 4; ++r) {
            #pragma unroll
            for (int m = 1; m < 16; m <<= 1) {
                es[r] += __shfl_xor(es[r], m, 64);
                unsigned x = __shfl_xor(km[r], m, 64);
                km[r] = x > km[r] ? x : km[r];
            }
        }
        if (l15 == 0) {
            #pragma unroll
            for (int r = 0; r < 4; ++r) {
                const int row = mTile * 128 + wvM * 64 + mi * 16 + quad * 4 + r;
                es_part [chunk * BS + row] = es[r];
                key_part[chunk * BS + row] = km[r];
            }
        }
    }
}

// ---------------------------------------------------------------------------
// Kernel 3: gather pred[i,label[i]] and sum_j pred[i,aux[i,j]]. One wave/row.
// ---------------------------------------------------------------------------
__global__ __launch_bounds__(256) void gather_kernel(
    const __bf16* __restrict__ fn, const __bf16* __restrict__ wn,
    const int* __restrict__ label, const int* __restrict__ aux,
    float* __restrict__ tgt, float* __restrict__ auxs)
{
    const int lane = threadIdx.x & 63;
    const int row  = blockIdx.x * 4 + (threadIdx.x >> 6);

    bf16x8 f8 = *((const bf16x8*)fn + (size_t)row * (EMB / 8) + lane);
    float fv[8];
    #pragma unroll
    for (int j = 0; j < 8; ++j) fv[j] = (float)f8[j];

    int cols[6];
    cols[0] = label[row];
    #pragma unroll
    for (int j = 0; j < NAUX; ++j) cols[j + 1] = aux[row * NAUX + j];

    float res[6];
    #pragma unroll
    for (int c = 0; c < 6; ++c) {
        bf16x8 w8 = *((const bf16x8*)wn + (size_t)cols[c] * (EMB / 8) + lane);
        float d = 0.f;
        #pragma unroll
        for (int j = 0; j < 8; ++j) d += fv[j] * (float)w8[j];
        #pragma unroll
        for (int m = 1; m < 64; m <<= 1) d += __shfl_xor(d, m, 64);
        res[c] = d;
    }
    if (lane == 0) {
        tgt[row]  = res[0] * 20.0f;
        auxs[row] = (res[1] + res[2] + res[3] + res[4] + res[5]) * 20.0f;
    }
}

// ---------------------------------------------------------------------------
// Kernel 4: combine 32 chunk partials per row -> loss_i, acc_i; block-reduce.
// loss_i = 20 + log(es) - 0.95*tgt_i - 0.01*auxsum_i
// ---------------------------------------------------------------------------
__global__ __launch_bounds__(256) void fin1_kernel(
    const float* __restrict__ es_part, const unsigned* __restrict__ key_part,
    const float* __restrict__ tgt, const float* __restrict__ auxs,
    const int* __restrict__ label, float* __restrict__ blk)
{
    const int row = blockIdx.x * 256 + threadIdx.x;
    float es = 0.f;
    unsigned k = 0u;
    #pragma unroll
    for (int c = 0; c < NCHUNK; ++c) {
        es += es_part[c * BS + row];
        unsigned x = key_part[c * BS + row];
        k = x > k ? x : k;
    }
    const int amax = 2047 - (int)(k & 0x7FFu);

    float loss = 20.0f + logf(es) - 0.95f * tgt[row] - 0.01f * auxs[row];
    float acc  = (amax == label[row]) ? 1.0f : 0.0f;

    #pragma unroll
    for (int m = 1; m < 64; m <<= 1) {
        loss += __shfl_xor(loss, m, 64);
        acc  += __shfl_xor(acc, m, 64);
    }
    __shared__ float sl[4], sa[4];
    const int wv = threadIdx.x >> 6;
    if ((threadIdx.x & 63) == 0) { sl[wv] = loss; sa[wv] = acc; }
    __syncthreads();
    if (threadIdx.x == 0) {
        blk[blockIdx.x]      = sl[0] + sl[1] + sl[2] + sl[3];
        blk[64 + blockIdx.x] = sa[0] + sa[1] + sa[2] + sa[3];
    }
}

__global__ __launch_bounds__(64) void fin2_kernel(
    const float* __restrict__ blk, float* __restrict__ out)
{
    float l = blk[threadIdx.x];
    float a = blk[64 + threadIdx.x];
    #pragma unroll
    for (int m = 1; m < 64; m <<= 1) {
        l += __shfl_xor(l, m, 64);
        a += __shfl_xor(a, m, 64);
    }
    if (threadIdx.x == 0) {
        out[0] = l / (float)BS;
        out[1] = a / (float)BS;
    }
}

// ---------------------------------------------------------------------------
// Workspace layout (bytes):
//   fn   @ 0         (16,777,216)  BS x 512 bf16
//   wn   @ 16777216  ( 2,097,152)  NCP(2048) x 512 bf16 (rows >=2000 zero)
//   es   @ 18874368  ( 2,097,152)  [32][BS] f32
//   key  @ 20971520  ( 2,097,152)  [32][BS] u32
//   tgt  @ 23068672  (    65,536)
//   auxs @ 23134208  (    65,536)
//   blk  @ 23199744  (       512)
// ---------------------------------------------------------------------------
extern "C" void kernel_launch(void* const* d_in, const int* in_sizes, int n_in,
                              void* d_out, int out_size, void* d_ws, size_t ws_size,
                              hipStream_t stream)
{
    const float* feat  = (const float*)d_in[0];
    const float* wemb  = (const float*)d_in[1];
    const int*   label = (const int*)d_in[2];
    const int*   aux   = (const int*)d_in[3];

    char* ws = (char*)d_ws;
    __bf16*   fn   = (__bf16*)(ws);
    __bf16*   wn   = (__bf16*)(ws + 16777216);
    float*    es   = (float*)(ws + 18874368);
    unsigned* key  = (unsigned*)(ws + 20971520);
    float*    tgt  = (float*)(ws + 23068672);
    float*    auxs = (float*)(ws + 23134208);
    float*    blk  = (float*)(ws + 23199744);
    float*    out  = (float*)d_out;

    hipLaunchKernelGGL(norm_kernel, dim3((BS + NCP) / 16), dim3(256), 0, stream,
                       feat, wemb, fn, wn);
    hipLaunchKernelGGL(main_kernel, dim3((BS / 128) * (NCP / 128)), dim3(256), 0, stream,
                       fn, wn, es, key);
    hipLaunchKernelGGL(gather_kernel, dim3(BS / 4), dim3(256), 0, stream,
                       fn, wn, label, aux, tgt, auxs);
    hipLaunchKernelGGL(fin1_kernel, dim3(BS / 256), dim3(256), 0, stream,
                       es, key, tgt, auxs, label, blk);
    hipLaunchKernelGGL(fin2_kernel, dim3(1), dim3(64), 0, stream, blk, out);
}

// Round 7
// 161.761 us; speedup vs baseline: 1.1533x; 1.0569x over previous
//
#include <hip/hip_runtime.h>
#include <hip/hip_bf16.h>
#include <stdint.h>

#define BS   16384
#define NC   2000
#define NCP  2048            // padded N (wn zero-filled rows 2000..2047)
#define EMB  512
#define NAUX 5
#define NCHUNK 32            // es/key partial chunks: nTile*2 + wvN
#define GBLK 4096            // gather/fin blocks (4 rows each)

typedef __bf16 bf16x8 __attribute__((ext_vector_type(8)));
typedef float  f32x4  __attribute__((ext_vector_type(4)));

// ---------------------------------------------------------------------------
// Kernel 1: row-normalize features (rows [0,BS)) and word_embed ([BS,BS+NC))
// into bf16; zero-fill wn padding rows [NC,NCP). 16 lanes per row.
// ---------------------------------------------------------------------------
__global__ __launch_bounds__(256) void norm_kernel(
    const float* __restrict__ feat, const float* __restrict__ wemb,
    __bf16* __restrict__ fn, __bf16* __restrict__ wn)
{
    const int sub = threadIdx.x & 15;                    // lane-in-row
    const int row = blockIdx.x * 16 + (threadIdx.x >> 4);

    if (row >= BS + NC) {  // padding rows of wn -> zeros (masked in epilogue)
        bf16x8 z = {};
        bf16x8* d = (bf16x8*)(wn + (size_t)(row - BS) * EMB) + sub * 4;
        #pragma unroll
        for (int i = 0; i < 4; ++i) d[i] = z;
        return;
    }
    const float* src;
    __bf16* dst;
    if (row < BS) { src = feat + (size_t)row * EMB;        dst = fn + (size_t)row * EMB; }
    else          { src = wemb + (size_t)(row - BS) * EMB; dst = wn + (size_t)(row - BS) * EMB; }

    const float4* s4 = (const float4*)src + sub * 8;     // 32 floats per lane
    float4 x[8];
    float ss = 0.f;
    #pragma unroll
    for (int i = 0; i < 8; ++i) {
        x[i] = s4[i];
        ss += x[i].x * x[i].x + x[i].y * x[i].y + x[i].z * x[i].z + x[i].w * x[i].w;
    }
    #pragma unroll
    for (int m = 1; m < 16; m <<= 1) ss += __shfl_xor(ss, m, 64);
    const float scale = 1.0f / fmaxf(sqrtf(ss), 1e-12f);

    bf16x8* d = (bf16x8*)dst + sub * 4;
    #pragma unroll
    for (int i = 0; i < 4; ++i) {
        bf16x8 o;
        o[0] = (__bf16)(x[2*i].x   * scale); o[1] = (__bf16)(x[2*i].y   * scale);
        o[2] = (__bf16)(x[2*i].z   * scale); o[3] = (__bf16)(x[2*i].w   * scale);
        o[4] = (__bf16)(x[2*i+1].x * scale); o[5] = (__bf16)(x[2*i+1].y * scale);
        o[6] = (__bf16)(x[2*i+1].z * scale); o[7] = (__bf16)(x[2*i+1].w * scale);
        d[i] = o;
    }
}

// ---------------------------------------------------------------------------
// Kernel 2: m97-structure GEMM with XCD-aware block swizzle.
//   Blocks round-robin across 8 XCDs (xcd = bid&7). Each XCD owns 16 mTiles,
//   iterated mTile-major: A-panel fetched once per chip into that XCD's L2;
//   wn (2 MB) stays L2-resident per XCD. Per-iter barrier drains become L2
//   hits (~200 cyc) instead of HBM misses (~900 cyc).
//   Staging via global_load_lds width=16 + explicit s_waitcnt(0) (builtin has
//   no SSA result; compiler will not wait for it). 16B-chunk XOR swizzle.
// mfma_f32_16x16x32_bf16 verified layouts:
//   A frag: lane(m=lane&15, q=lane>>4) holds A[m][q*8+j]
//   B frag: lane(n=lane&15, q)         holds B[q*8+j][n] = wn[n][q*8+j]
//   C/D:    col(n) = lane&15, row(m) = q*4 + reg
// ---------------------------------------------------------------------------
__global__ __launch_bounds__(256) void main_kernel(
    const __bf16* __restrict__ fn, const __bf16* __restrict__ wn,
    float* __restrict__ es_part, unsigned* __restrict__ key_part)
{
    __shared__ __align__(16) __bf16 As[128 * 64];
    __shared__ __align__(16) __bf16 Bs[128 * 64];

    const int tid   = threadIdx.x;
    const int lane  = tid & 63;
    const int l15   = lane & 15;
    const int quad  = lane >> 4;
    const int wv    = tid >> 6;
    const int wvM   = wv >> 1;
    const int wvN   = wv & 1;
    // XCD swizzle: xcd = bid&7 -> mTiles [xcd*16, xcd*16+16), mTile-major.
    const int xcd   = blockIdx.x & 7;
    const int j     = blockIdx.x >> 3;           // 0..255 within XCD
    const int mTile = xcd * 16 + (j >> 4);       // 0..127
    const int nTile = j & 15;                    // 0..15

    const __bf16* fbase = fn + (size_t)mTile * 128 * EMB;
    const __bf16* wbase = wn + (size_t)nTile * 128 * EMB;

    // Per-lane staging geometry: slot = wv*4+j covers LDS rows slot*8..+8.
    const int sRowIn = lane >> 3;                 // 0..7
    const int sChunk = (lane & 7) ^ sRowIn;       // logical 16B chunk to fetch
    f32x4 acc[4][4] = {};

    for (int kk = 0; kk < EMB; kk += 64) {
        __syncthreads();                          // previous tile's readers done
        #pragma unroll
        for (int p = 0; p < 4; ++p) {
            const int slot = wv * 4 + p;
            const size_t goff = (size_t)(slot * 8 + sRowIn) * EMB + kk + sChunk * 8;
            __builtin_amdgcn_global_load_lds(
                (const __attribute__((address_space(1))) void*)(fbase + goff),
                (__attribute__((address_space(3))) void*)(As + slot * 512), 16, 0, 0);
            __builtin_amdgcn_global_load_lds(
                (const __attribute__((address_space(1))) void*)(wbase + goff),
                (__attribute__((address_space(3))) void*)(Bs + slot * 512), 16, 0, 0);
        }
        __builtin_amdgcn_s_waitcnt(0);            // drain global->LDS DMA
        __syncthreads();                          // staged tile visible to all

        #pragma unroll
        for (int kc = 0; kc < 2; ++kc) {
            bf16x8 aF[4], bF[4];
            #pragma unroll
            for (int i = 0; i < 4; ++i) {
                const int ar = wvM * 64 + i * 16 + l15;
                const int br = wvN * 64 + i * 16 + l15;
                const int ca = ((kc * 4 + quad) ^ (ar & 7)) * 8;
                const int cb = ((kc * 4 + quad) ^ (br & 7)) * 8;
                aF[i] = *(const bf16x8*)(As + ar * 64 + ca);
                bF[i] = *(const bf16x8*)(Bs + br * 64 + cb);
            }
            #pragma unroll
            for (int mi = 0; mi < 4; ++mi)
                #pragma unroll
                for (int ni = 0; ni < 4; ++ni)
                    acc[mi][ni] = __builtin_amdgcn_mfma_f32_16x16x32_bf16(
                        aF[mi], bF[ni], acc[mi][ni], 0, 0, 0);
        }
    }

    // Epilogue: es += exp2((v-1)*20*log2e); packed argmax; per-(nTile,wvN) chunk.
    const float C20 = 28.853900817779268f;  // 20*log2(e)
    const int chunk = nTile * 2 + wvN;
    #pragma unroll
    for (int mi = 0; mi < 4; ++mi) {
        float    es[4] = {0.f, 0.f, 0.f, 0.f};
        unsigned km[4] = {0u, 0u, 0u, 0u};
        #pragma unroll
        for (int ni = 0; ni < 4; ++ni) {
            const int col = nTile * 128 + wvN * 64 + ni * 16 + l15;
            const unsigned colenc = 2047u - (unsigned)col;
            const bool valid = (col < NC);
            #pragma unroll
            for (int r = 0; r < 4; ++r) {
                float v = valid ? acc[mi][ni][r] : -3.0f;
                es[r] += exp2f((v - 1.0f) * C20);
                unsigned u = __float_as_uint(v);
                unsigned k = u ^ (unsigned)(((int)u >> 31) | 0x80000000);
                unsigned pk = (k & 0xFFFFF800u) | colenc;  // bigger v, then smaller col
                km[r] = pk > km[r] ? pk : km[r];
            }
        }
        #pragma unroll
        for (int r = 0; r < 4; ++r) {
            #pragma unroll
            for (int m = 1; m < 16; m <<= 1) {
                es[r] += __shfl_xor(es[r], m, 64);
                unsigned x = __shfl_xor(km[r], m, 64);
                km[r] = x > km[r] ? x : km[r];
            }
        }
        if (l15 == 0) {
            #pragma unroll
            for (int r = 0; r < 4; ++r) {
                const int row = mTile * 128 + wvM * 64 + mi * 16 + quad * 4 + r;
                es_part [chunk * BS + row] = es[r];
                key_part[chunk * BS + row] = km[r];
            }
        }
    }
}

// ---------------------------------------------------------------------------
// Kernel 3: gather + finalize-stage-1. One wave per row:
//   - 6 dots (label + 5 aux) of length 512 vs wn
//   - combine the 32 es/key chunk partials for this row
//   - loss_i = 20 + log(es) - 0.95*tgt - 0.01*auxsum ; acc_i = amax==label
//   - block partial (4 rows) -> blkpart
// ---------------------------------------------------------------------------
__global__ __launch_bounds__(256) void gather_fin_kernel(
    const __bf16* __restrict__ fn, const __bf16* __restrict__ wn,
    const int* __restrict__ label, const int* __restrict__ aux,
    const float* __restrict__ es_part, const unsigned* __restrict__ key_part,
    float* __restrict__ blkpart)
{
    const int lane = threadIdx.x & 63;
    const int wv   = threadIdx.x >> 6;
    const int row  = blockIdx.x * 4 + wv;

    bf16x8 f8 = *((const bf16x8*)fn + (size_t)row * (EMB / 8) + lane);
    float fv[8];
    #pragma unroll
    for (int j = 0; j < 8; ++j) fv[j] = (float)f8[j];

    const int lab = label[row];
    int cols[6];
    cols[0] = lab;
    #pragma unroll
    for (int j = 0; j < NAUX; ++j) cols[j + 1] = aux[row * NAUX + j];

    float res[6];
    #pragma unroll
    for (int c = 0; c < 6; ++c) {
        bf16x8 w8 = *((const bf16x8*)wn + (size_t)cols[c] * (EMB / 8) + lane);
        float d = 0.f;
        #pragma unroll
        for (int j = 0; j < 8; ++j) d += fv[j] * (float)w8[j];
        #pragma unroll
        for (int m = 1; m < 64; m <<= 1) d += __shfl_xor(d, m, 64);
        res[c] = d;   // all lanes hold the full dot after butterfly
    }
    const float tgt  = res[0] * 20.0f;
    const float auxs = (res[1] + res[2] + res[3] + res[4] + res[5]) * 20.0f;

    // Combine 32 chunk partials: lane c (and c+32 duplicate) loads chunk c.
    const int c = lane & 31;
    float    es = es_part [c * BS + row];
    unsigned k  = key_part[c * BS + row];
    #pragma unroll
    for (int m = 1; m < 32; m <<= 1) {
        es += __shfl_xor(es, m, 64);
        unsigned x = __shfl_xor(k, m, 64);
        k = x > k ? x : k;
    }
    const int amax = 2047 - (int)(k & 0x7FFu);
    const float loss = 20.0f + logf(es) - 0.95f * tgt - 0.01f * auxs;
    const float acc  = (amax == lab) ? 1.0f : 0.0f;

    __shared__ float sl[4], sa[4];
    if (lane == 0) { sl[wv] = loss; sa[wv] = acc; }
    __syncthreads();
    if (threadIdx.x == 0) {
        blkpart[blockIdx.x]        = sl[0] + sl[1] + sl[2] + sl[3];
        blkpart[GBLK + blockIdx.x] = sa[0] + sa[1] + sa[2] + sa[3];
    }
}

// ---------------------------------------------------------------------------
// Kernel 4: final reduction of 4096 block partials -> (loss, acc).
// ---------------------------------------------------------------------------
__global__ __launch_bounds__(256) void fin2_kernel(
    const float* __restrict__ blkpart, float* __restrict__ out)
{
    float l = 0.f, a = 0.f;
    for (int i = threadIdx.x; i < GBLK; i += 256) {
        l += blkpart[i];
        a += blkpart[GBLK + i];
    }
    #pragma unroll
    for (int m = 1; m < 64; m <<= 1) {
        l += __shfl_xor(l, m, 64);
        a += __shfl_xor(a, m, 64);
    }
    __shared__ float sl[4], sa[4];
    const int wv = threadIdx.x >> 6;
    if ((threadIdx.x & 63) == 0) { sl[wv] = l; sa[wv] = a; }
    __syncthreads();
    if (threadIdx.x == 0) {
        out[0] = (sl[0] + sl[1] + sl[2] + sl[3]) / (float)BS;
        out[1] = (sa[0] + sa[1] + sa[2] + sa[3]) / (float)BS;
    }
}

// ---------------------------------------------------------------------------
// Workspace layout (bytes):
//   fn      @ 0         (16,777,216)  BS x 512 bf16
//   wn      @ 16777216  ( 2,097,152)  NCP(2048) x 512 bf16 (rows >=2000 zero)
//   es      @ 18874368  ( 2,097,152)  [32][BS] f32
//   key     @ 20971520  ( 2,097,152)  [32][BS] u32
//   blkpart @ 23068672  (    32,768)  [2][4096] f32
// ---------------------------------------------------------------------------
extern "C" void kernel_launch(void* const* d_in, const int* in_sizes, int n_in,
                              void* d_out, int out_size, void* d_ws, size_t ws_size,
                              hipStream_t stream)
{
    const float* feat  = (const float*)d_in[0];
    const float* wemb  = (const float*)d_in[1];
    const int*   label = (const int*)d_in[2];
    const int*   aux   = (const int*)d_in[3];

    char* ws = (char*)d_ws;
    __bf16*   fn      = (__bf16*)(ws);
    __bf16*   wn      = (__bf16*)(ws + 16777216);
    float*    es      = (float*)(ws + 18874368);
    unsigned* key     = (unsigned*)(ws + 20971520);
    float*    blkpart = (float*)(ws + 23068672);
    float*    out     = (float*)d_out;

    hipLaunchKernelGGL(norm_kernel, dim3((BS + NCP) / 16), dim3(256), 0, stream,
                       feat, wemb, fn, wn);
    hipLaunchKernelGGL(main_kernel, dim3((BS / 128) * (NCP / 128)), dim3(256), 0, stream,
                       fn, wn, es, key);
    hipLaunchKernelGGL(gather_fin_kernel, dim3(GBLK), dim3(256), 0, stream,
                       fn, wn, label, aux, es, key, blkpart);
    hipLaunchKernelGGL(fin2_kernel, dim3(1), dim3(256), 0, stream, blkpart, out);
}